// Round 10
// baseline (2367.443 us; speedup 1.0000x reference)
//
#include <hip/hip_runtime.h>

#define DM 256
#define NH 4
#define HD 64
#define DEG 32
#define LQ 33
#define DOUT 128
#define NTHREADS 256

typedef __attribute__((ext_vector_type(8))) short bf8v;   // 8 bf16 = 4 VGPRs (MFMA A/B frag)
typedef __attribute__((ext_vector_type(4))) float f4v;    // MFMA C/D frag

__device__ __forceinline__ float b2f(unsigned short u){ union{unsigned int i;float f;}v; v.i=((unsigned int)u)<<16; return v.f; }
__device__ __forceinline__ unsigned short f2b(float f){
  union{float f;unsigned int i;}v; v.f=f;
  unsigned int r=v.i+0x7FFFu+((v.i>>16)&1u);
  return (unsigned short)(r>>16);
}
__device__ __forceinline__ float wred(float x){
  #pragma unroll
  for (int o=32;o>=1;o>>=1) x += __shfl_xor(x,o,64);
  return x;
}

// XOR swizzles for bf16 LDS tiles read as ds_read_b128 A/B-fragments
__device__ __forceinline__ int swz (int r, int c){ return r*DM  + (((c>>3) ^ (r&7))<<3) + (c&7); } // [R][256]
__device__ __forceinline__ int swz2(int r, int c){ return r*128 + (((c>>3) ^ (r&7))<<3) + (c&7); } // [R][128]
__device__ __forceinline__ int swzV(int r, int c){ return r*HD  + (((c>>3) ^ (r&7))<<3) + (c&7); } // [R][64]

// pack 8 consecutive f32 (global H) into a bf16 A-fragment via v_cvt_pk_bf16_f32
__device__ __forceinline__ bf8v h2frag(const float* p){
  const float4 a = *(const float4*)p;
  const float4 b = *(const float4*)(p+4);
  unsigned int r0,r1,r2,r3;
  asm("v_cvt_pk_bf16_f32 %0,%1,%2" : "=v"(r0) : "v"(a.x), "v"(a.y));
  asm("v_cvt_pk_bf16_f32 %0,%1,%2" : "=v"(r1) : "v"(a.z), "v"(a.w));
  asm("v_cvt_pk_bf16_f32 %0,%1,%2" : "=v"(r2) : "v"(b.x), "v"(b.y));
  asm("v_cvt_pk_bf16_f32 %0,%1,%2" : "=v"(r3) : "v"(b.z), "v"(b.w));
  union{unsigned int u[4]; bf8v v;} c;
  c.u[0]=r0; c.u[1]=r1; c.u[2]=r2; c.u[3]=r3;
  return c.v;
}

// B-fragment: W[row][e..e+7] as bf16; fold1/fold2 only used on the f32 fallback path
template<bool BF>
__device__ __forceinline__ bf8v wfrag(const float* Wf, const unsigned short* Wb,
                                      const float* fold1, const float* fold2, int row, int e){
  if constexpr (BF) {
    return *(const bf8v*)(Wb + (size_t)row*DM + e);
  } else {
    const float* p = Wf + (size_t)row*DM + e;
    float4 a = *(const float4*)p;
    float4 b = *(const float4*)(p+4);
    if (fold1) {
      const float4 fa = *(const float4*)(fold1+e), fb = *(const float4*)(fold1+e+4);
      a.x*=fa.x; a.y*=fa.y; a.z*=fa.z; a.w*=fa.w;
      b.x*=fb.x; b.y*=fb.y; b.z*=fb.z; b.w*=fb.w;
    }
    if (fold2) {
      const float4 fa = *(const float4*)(fold2+e), fb = *(const float4*)(fold2+e+4);
      a.x*=fa.x; a.y*=fa.y; a.z*=fa.z; a.w*=fa.w;
      b.x*=fb.x; b.y*=fb.y; b.z*=fb.z; b.w*=fb.w;
    }
    bf8v r;
    r[0]=(short)f2b(a.x); r[1]=(short)f2b(a.y); r[2]=(short)f2b(a.z); r[3]=(short)f2b(a.w);
    r[4]=(short)f2b(b.x); r[5]=(short)f2b(b.y); r[6]=(short)f2b(b.z); r[7]=(short)f2b(b.w);
    return r;
  }
}

__device__ __forceinline__ f4v mfma16(bf8v a, bf8v b, f4v c){
  return __builtin_amdgcn_mfma_f32_16x16x32_bf16(a, b, c, 0, 0, 0);
}

// LDS plan (u16 offsets in U):
//   [0,6144)      Q[48][128]  (2 heads; P overlays per-head col slice after scores)
//   [6144,12288)  K[48][128]
//   [12288,20480) VT[2][64][64] (keys 48..63 stay zero)
//   [0,12288)     mid[48][256] after attention (Q/K dead)
//   [20480,32768) AOall[48][256] -> X1 -> Z
#define U_Q  0
#define U_K  6144
#define U_VT 12288
#define RB   20480
#define U_SZ 32768

template<bool WBF16>
__global__ __launch_bounds__(NTHREADS, 1) void smtp_center(
    const float* __restrict__ H,
    const int* __restrict__ dstE,
    const int* __restrict__ centers,
    const float* __restrict__ target,
    const float* __restrict__ ln_in_w,
    const float* __restrict__ ln1_w,
    const float* __restrict__ ln2_w,
    const float* __restrict__ w_qkv,
    const float* __restrict__ b_qkv,
    const float* __restrict__ w_o,
    const float* __restrict__ b_o,
    const float* __restrict__ w_gate,
    const float* __restrict__ w_up,
    const float* __restrict__ w_down,
    const float* __restrict__ w_head,
    const float* __restrict__ b_head,
    const unsigned short* __restrict__ wb,
    float* __restrict__ partial)
{
  __shared__ __align__(16) unsigned short U[U_SZ];
  __shared__ float sS0[48];        // rsH  (0 on pad rows)
  __shared__ float sS1[48];        // rsH*rs2 (QKV C-scale; 0 on pad rows)
  __shared__ float sRowSum[48*4];
  __shared__ int sIdx[48];
  __shared__ float sRed[4];

  const unsigned short* wbQKV = wb;
  const unsigned short* wbO   = wb + 196608;
  const unsigned short* wbG   = wb + 262144;
  const unsigned short* wbU   = wb + 327680;
  const unsigned short* wbD   = wb + 393216;
  const unsigned short* wbH   = wb + 458752;

  const int tid  = threadIdx.x;
  const int lane = tid & 63;
  const int wave = tid >> 6;
  const int bid  = blockIdx.x;
  const int l15  = lane & 15;
  const int l16  = (lane >> 4) * 8;
  const int rsub = (lane >> 4) * 4;

  // P0: star indices (pad rows -> 0, masked later by sS0/sS1 = 0)
  if (tid < 48) {
    int ctr = centers[bid];
    sIdx[tid] = (tid == 0) ? ctr : (tid < 1+DEG ? dstE[(size_t)ctr*DEG + (tid-1)] : 0);
  }
  __syncthreads();

  // P1: per-row scales (no activation staging) + VT pad zero
  for (int r = wave; r < 48; r += 4) {
    if (r < LQ) {
      const float4 x4 = ((const float4*)(H + (size_t)sIdx[r]*DM))[lane];
      const float4 wi = ((const float4*)ln_in_w)[lane];
      float ssh = x4.x*x4.x + x4.y*x4.y + x4.z*x4.z + x4.w*x4.w;
      const float w0 = x4.x*wi.x, w1 = x4.y*wi.y, w2 = x4.z*wi.z, w3 = x4.w*wi.w;
      float ssw = w0*w0 + w1*w1 + w2*w2 + w3*w3;
      ssh = wred(ssh);
      ssw = wred(ssw);
      if (lane == 0) {
        const float rsH = rsqrtf(ssh*(1.f/DM) + 1e-6f);
        const float rs2 = rsqrtf(rsH*rsH*ssw*(1.f/DM) + 1e-6f);
        sS0[r] = rsH;
        sS1[r] = rsH*rs2;
      }
    } else if (lane == 0) { sS0[r] = 0.f; sS1[r] = 0.f; }
  }
  {  // VT[2][64][64] keys 48..63 = 0 once (QKV writes only keys 0..47)
    const int hh = tid >> 7;           // 0..1
    const int d  = (tid >> 1) & 63;
    const int ch = 6 + (tid & 1);
    *(uint4*)&U[U_VT + hh*4096 + d*HD + ((ch ^ (d&7))<<3)] = make_uint4(0,0,0,0);
  }
  __syncthreads();

  // hoist QKV C-scale per fragment row
  float s1v[3][4];
  #pragma unroll
  for (int m = 0; m < 3; ++m)
    #pragma unroll
    for (int j = 0; j < 4; ++j)
      s1v[m][j] = sS1[m*16 + rsub + j];

  // P2: head-pair loop: QKV(2h) | bar | scores+softmax(2h) | bar | PV(2h)->AOall | bar
  for (int hp = 0; hp < 2; ++hp) {
    // 2a QKV: M=48 x N=384 (2 heads x Q|K|V), K=256; k-outer; A from global H (L1-hot)
    {
      int wrow[2][3], sect[3], cc[3];
      #pragma unroll
      for (int t3 = 0; t3 < 3; ++t3) {
        const int t = wave*3 + t3;           // tile within head, 0..11
        sect[t3] = t >> 2;                   // 0=Q 1=K 2=V
        cc[t3] = (t & 3)*16 + l15;           // 0..63 within head
        #pragma unroll
        for (int hh = 0; hh < 2; ++hh)
          wrow[hh][t3] = sect[t3]*DM + (hp*2+hh)*HD + cc[t3];
      }
      const float* rp[3];
      #pragma unroll
      for (int m = 0; m < 3; ++m)
        rp[m] = H + (size_t)sIdx[m*16 + l15]*DM + l16;
      f4v acc[2][3][3];
      #pragma unroll
      for (int hh = 0; hh < 2; ++hh)
        #pragma unroll
        for (int t3 = 0; t3 < 3; ++t3)
          #pragma unroll
          for (int m = 0; m < 3; ++m)
            acc[hh][t3][m] = (f4v){0.f,0.f,0.f,0.f};
      #pragma unroll
      for (int k = 0; k < 8; ++k) {
        bf8v aF[3];
        #pragma unroll
        for (int m = 0; m < 3; ++m)
          aF[m] = h2frag(rp[m] + k*32);
        #pragma unroll
        for (int hh = 0; hh < 2; ++hh)
          #pragma unroll
          for (int t3 = 0; t3 < 3; ++t3) {
            const bf8v b = wfrag<WBF16>(w_qkv, wbQKV, ln_in_w, ln1_w, wrow[hh][t3], k*32 + l16);
            #pragma unroll
            for (int m = 0; m < 3; ++m)
              acc[hh][t3][m] = mfma16(aF[m], b, acc[hh][t3][m]);
          }
      }
      #pragma unroll
      for (int hh = 0; hh < 2; ++hh)
        #pragma unroll
        for (int t3 = 0; t3 < 3; ++t3) {
          const float bias = b_qkv[wrow[hh][t3]];
          const int c = cc[t3];
          if (sect[t3] == 2) {               // V -> VT[hh][d][key]
            #pragma unroll
            for (int m = 0; m < 3; ++m)
              #pragma unroll
              for (int j = 0; j < 4; ++j)
                U[U_VT + hh*4096 + swzV(c, m*16 + rsub + j)] = f2b(acc[hh][t3][m][j]*s1v[m][j] + bias);
          } else {
            unsigned short* dstb = U + (sect[t3] ? U_K : U_Q);
            #pragma unroll
            for (int m = 0; m < 3; ++m)
              #pragma unroll
              for (int j = 0; j < 4; ++j)
                dstb[swz2(m*16 + rsub + j, hh*64 + c)] = f2b(acc[hh][t3][m][j]*s1v[m][j] + bias);
          }
        }
    }
    __syncthreads();

    // 2b scores + in-register softmax: 6 tasks (hh,qm) over 4 waves (waves 0,1 take 2)
    #pragma unroll
    for (int ti = 0; ti < 2; ++ti) {
      const int t = wave + ti*4;
      if (t < 6) {
        const int hh = t / 3, qm = t % 3;
        f4v s3[3];
        s3[0] = (f4v){0.f,0.f,0.f,0.f}; s3[1] = s3[0]; s3[2] = s3[0];
        #pragma unroll
        for (int kk = 0; kk < 2; ++kk) {
          const bf8v a = *(const bf8v*)(U + U_Q + swz2(qm*16 + l15, hh*64 + kk*32 + l16));
          #pragma unroll
          for (int nk = 0; nk < 3; ++nk) {
            const bf8v bb = *(const bf8v*)(U + U_K + swz2(nk*16 + l15, hh*64 + kk*32 + l16));
            s3[nk] = mfma16(a, bb, s3[nk]);
          }
        }
        #pragma unroll
        for (int j = 0; j < 4; ++j) {
          const float v0 = s3[0][j]*0.125f;
          const float v1 = s3[1][j]*0.125f;
          const float v2 = (l15 >= 1) ? -INFINITY : s3[2][j]*0.125f;  // keys 33..47 masked
          float mx = fmaxf(fmaxf(v0, v1), v2);
          mx = fmaxf(mx, __shfl_xor(mx, 1, 64));
          mx = fmaxf(mx, __shfl_xor(mx, 2, 64));
          mx = fmaxf(mx, __shfl_xor(mx, 4, 64));
          mx = fmaxf(mx, __shfl_xor(mx, 8, 64));
          const float e0 = __expf(v0 - mx), e1 = __expf(v1 - mx), e2 = __expf(v2 - mx);
          float den = e0 + e1 + e2;
          den += __shfl_xor(den, 1, 64);
          den += __shfl_xor(den, 2, 64);
          den += __shfl_xor(den, 4, 64);
          den += __shfl_xor(den, 8, 64);
          const float rn = 1.f / den;
          const int row = qm*16 + rsub + j;
          U[U_Q + swz2(row, hh*64 + 0*16 + l15)] = f2b(e0 * rn);
          U[U_Q + swz2(row, hh*64 + 1*16 + l15)] = f2b(e1 * rn);
          U[U_Q + swz2(row, hh*64 + 2*16 + l15)] = f2b(e2 * rn);
        }
      }
    }
    __syncthreads();

    // 2c PV: 8 tasks (hh, d-tile=wave); K=64 keys (33..47 P=0; 48..63 Pgarbage x VT0 = 0)
    #pragma unroll
    for (int hh = 0; hh < 2; ++hh) {
      f4v o4[3];
      o4[0] = (f4v){0.f,0.f,0.f,0.f}; o4[1] = o4[0]; o4[2] = o4[0];
      #pragma unroll
      for (int kk = 0; kk < 2; ++kk) {
        const bf8v bb = *(const bf8v*)(U + U_VT + hh*4096 + swzV(wave*16 + l15, kk*32 + l16));
        #pragma unroll
        for (int mq = 0; mq < 3; ++mq) {
          const bf8v a = *(const bf8v*)(U + U_Q + swz2(mq*16 + l15, hh*64 + kk*32 + l16));
          o4[mq] = mfma16(a, bb, o4[mq]);
        }
      }
      #pragma unroll
      for (int mq = 0; mq < 3; ++mq)
        #pragma unroll
        for (int j = 0; j < 4; ++j)
          U[RB + swz(mq*16 + rsub + j, (hp*2+hh)*64 + wave*16 + l15)] = f2b(o4[mq][j]);
    }
    __syncthreads();
  }

  // P3: WO-all: X1 = X0 + AOall @ w_o^T ; X0 recomputed from global H; rowsums for rs3
  {
    f4v acc[3][4];
    #pragma unroll
    for (int t4 = 0; t4 < 4; ++t4) {
      const int col = wave*64 + t4*16 + l15;
      const float bo = b_o[col];
      const float wi = ln_in_w[col];
      #pragma unroll
      for (int m = 0; m < 3; ++m)
        #pragma unroll
        for (int j = 0; j < 4; ++j) {
          const int row = m*16 + rsub + j;
          acc[m][t4][j] = sS0[row]*H[(size_t)sIdx[row]*DM + col]*wi + bo;
        }
    }
    #pragma unroll
    for (int k = 0; k < 8; ++k) {
      bf8v aA[3];
      #pragma unroll
      for (int m = 0; m < 3; ++m)
        aA[m] = *(const bf8v*)(U + RB + swz(m*16 + l15, k*32 + l16));
      #pragma unroll
      for (int t4 = 0; t4 < 4; ++t4) {
        const int col = wave*64 + t4*16 + l15;
        const bf8v b = wfrag<WBF16>(w_o, wbO, nullptr, nullptr, col, k*32 + l16);
        #pragma unroll
        for (int m = 0; m < 3; ++m)
          acc[m][t4] = mfma16(aA[m], b, acc[m][t4]);
      }
    }
    // per-row sumsq partials for rmsnorm(X1)
    #pragma unroll
    for (int m = 0; m < 3; ++m)
      #pragma unroll
      for (int j = 0; j < 4; ++j) {
        float p = 0.f;
        #pragma unroll
        for (int t4 = 0; t4 < 4; ++t4) p += acc[m][t4][j]*acc[m][t4][j];
        p += __shfl_xor(p, 1, 64);
        p += __shfl_xor(p, 2, 64);
        p += __shfl_xor(p, 4, 64);
        p += __shfl_xor(p, 8, 64);
        if (l15 == 0) sRowSum[(m*16 + rsub + j)*4 + wave] = p;
      }
    __syncthreads();   // all AOall reads complete before X1 overwrites RB
    #pragma unroll
    for (int t4 = 0; t4 < 4; ++t4) {
      const int col = wave*64 + t4*16 + l15;
      #pragma unroll
      for (int m = 0; m < 3; ++m)
        #pragma unroll
        for (int j = 0; j < 4; ++j)
          U[RB + swz(m*16 + rsub + j, col)] = f2b(acc[m][t4][j]);
    }
  }
  __syncthreads();

  // P4: mid = silu(rs3*X1@Wg''^T) * (rs3*X1@Wu''^T) -> U[0,12288); k-outer, 2 passes
  #pragma unroll
  for (int p = 0; p < 2; ++p) {
    f4v aG[2][3], aU[2][3];
    #pragma unroll
    for (int tt = 0; tt < 2; ++tt)
      #pragma unroll
      for (int m = 0; m < 3; ++m) { aG[tt][m] = (f4v){0.f,0.f,0.f,0.f}; aU[tt][m] = aG[tt][m]; }
    #pragma unroll
    for (int k = 0; k < 8; ++k) {
      bf8v aF[3];
      #pragma unroll
      for (int m = 0; m < 3; ++m)
        aF[m] = *(const bf8v*)(U + RB + swz(m*16 + l15, k*32 + l16));
      #pragma unroll
      for (int tt = 0; tt < 2; ++tt) {
        const int col = wave*64 + (p*2 + tt)*16 + l15;
        const bf8v bg = wfrag<WBF16>(w_gate, wbG, ln2_w, nullptr, col, k*32 + l16);
        const bf8v bu = wfrag<WBF16>(w_up,   wbU, ln2_w, nullptr, col, k*32 + l16);
        #pragma unroll
        for (int m = 0; m < 3; ++m) {
          aG[tt][m] = mfma16(aF[m], bg, aG[tt][m]);
          aU[tt][m] = mfma16(aF[m], bu, aU[tt][m]);
        }
      }
    }
    #pragma unroll
    for (int tt = 0; tt < 2; ++tt) {
      const int col = wave*64 + (p*2 + tt)*16 + l15;
      #pragma unroll
      for (int m = 0; m < 3; ++m)
        #pragma unroll
        for (int j = 0; j < 4; ++j) {
          const int row = m*16 + rsub + j;
          const float tot = sRowSum[row*4+0] + sRowSum[row*4+1] + sRowSum[row*4+2] + sRowSum[row*4+3];
          const float rs3 = rsqrtf(tot*(1.f/DM) + 1e-6f);
          const float g = aG[tt][m][j]*rs3;
          const float uu = aU[tt][m][j]*rs3;
          const float v = (g / (1.f + __expf(-g))) * uu;
          U[swz(row, col)] = f2b(v);
        }
    }
  }
  __syncthreads();

  // P5: Z = X1 + mid @ w_down^T; C-init from X1 (own cols); Z -> RB (own cols)
  {
    f4v acc[3][4];
    #pragma unroll
    for (int t4 = 0; t4 < 4; ++t4) {
      const int col = wave*64 + t4*16 + l15;
      #pragma unroll
      for (int m = 0; m < 3; ++m)
        #pragma unroll
        for (int j = 0; j < 4; ++j)
          acc[m][t4][j] = b2f(U[RB + swz(m*16 + rsub + j, col)]);
    }
    #pragma unroll
    for (int k = 0; k < 8; ++k) {
      bf8v aM[3];
      #pragma unroll
      for (int m = 0; m < 3; ++m)
        aM[m] = *(const bf8v*)(U + swz(m*16 + l15, k*32 + l16));
      #pragma unroll
      for (int t4 = 0; t4 < 4; ++t4) {
        const int col = wave*64 + t4*16 + l15;
        const bf8v b = wfrag<WBF16>(w_down, wbD, nullptr, nullptr, col, k*32 + l16);
        #pragma unroll
        for (int m = 0; m < 3; ++m)
          acc[m][t4] = mfma16(aM[m], b, acc[m][t4]);
      }
    }
    #pragma unroll
    for (int t4 = 0; t4 < 4; ++t4) {
      const int col = wave*64 + t4*16 + l15;
      #pragma unroll
      for (int m = 0; m < 3; ++m)
        #pragma unroll
        for (int j = 0; j < 4; ++j)
          U[RB + swz(m*16 + rsub + j, col)] = f2b(acc[m][t4][j]);
    }
  }
  __syncthreads();

  // P6: head GEMM on rows 1..32 (Z in RB) + MSE vs gathered targets; k-outer
  float lsum = 0.f;
  {
    int cols[2]; f4v acc[2][2];
    #pragma unroll
    for (int t2 = 0; t2 < 2; ++t2) {
      cols[t2] = (wave*2 + t2)*16 + l15;   // 0..127
      const float bh = b_head[cols[t2]];
      acc[t2][0] = (f4v){bh,bh,bh,bh}; acc[t2][1] = acc[t2][0];
    }
    #pragma unroll
    for (int k = 0; k < 8; ++k) {
      bf8v aH[2];
      #pragma unroll
      for (int m = 0; m < 2; ++m)
        aH[m] = *(const bf8v*)(U + RB + swz(1 + m*16 + l15, k*32 + l16));
      #pragma unroll
      for (int t2 = 0; t2 < 2; ++t2) {
        const bf8v b = wfrag<WBF16>(w_head, wbH, nullptr, nullptr, cols[t2], k*32 + l16);
        #pragma unroll
        for (int m = 0; m < 2; ++m)
          acc[t2][m] = mfma16(aH[m], b, acc[t2][m]);
      }
    }
    #pragma unroll
    for (int t2 = 0; t2 < 2; ++t2)
      #pragma unroll
      for (int m = 0; m < 2; ++m)
        #pragma unroll
        for (int j = 0; j < 4; ++j) {
          const int row = 1 + m*16 + rsub + j;          // 1..32
          const float tv = target[(size_t)sIdx[row]*DOUT + cols[t2]];
          const float d = acc[t2][m][j] - tv;
          lsum += d*d;
        }
  }
  lsum = wred(lsum);
  if (lane == 0) sRed[wave] = lsum;
  __syncthreads();
  if (tid == 0)
    partial[bid] = (sRed[0]+sRed[1]+sRed[2]+sRed[3]) * (1.f/(DEG*DOUT));
}

// one-time (per launch) f32 -> bf16 weight conversion into d_ws, with RMSNorm-weight folding:
//   Wqkv'' = Wqkv * ln_in_w * ln1_w (k-dim); Wg''/Wu'' = W * ln2_w (k-dim); others plain.
__global__ void cvt_w(const float* __restrict__ qkv, const float* __restrict__ o,
                      const float* __restrict__ g, const float* __restrict__ u,
                      const float* __restrict__ dn, const float* __restrict__ hd,
                      const float* __restrict__ lin, const float* __restrict__ l1,
                      const float* __restrict__ l2,
                      unsigned short* __restrict__ out)
{
  const int i = blockIdx.x*NTHREADS + threadIdx.x;
  const int e = i*2;
  if (e >= 491520) return;
  const float* src; int off;
  float f0 = 1.f, f1 = 1.f;
  if      (e < 196608){ src=qkv; off=e;        const int c=off&255; f0=lin[c]*l1[c]; f1=lin[c+1]*l1[c+1]; }
  else if (e < 262144){ src=o;  off=e-196608; }
  else if (e < 327680){ src=g;  off=e-262144;  const int c=off&255; f0=l2[c]; f1=l2[c+1]; }
  else if (e < 393216){ src=u;  off=e-327680;  const int c=off&255; f0=l2[c]; f1=l2[c+1]; }
  else if (e < 458752){ src=dn; off=e-393216; }
  else                { src=hd; off=e-458752; }
  const float2 v = *(const float2*)(src + off);
  const unsigned int pk = (unsigned int)f2b(v.x*f0) | ((unsigned int)f2b(v.y*f1) << 16);
  *(unsigned int*)(out + e) = pk;
}

__global__ void smtp_reduce(const float* __restrict__ partial, int B, float* __restrict__ out)
{
  __shared__ float sRed[4];
  const int tid = threadIdx.x;
  float s = 0.f;
  for (int i = tid; i < B; i += NTHREADS) s += partial[i];
  s = wred(s);
  if ((tid & 63) == 0) sRed[tid>>6] = s;
  __syncthreads();
  if (tid == 0) out[0] = (sRed[0]+sRed[1]+sRed[2]+sRed[3]) / (float)B;
}

extern "C" void kernel_launch(void* const* d_in, const int* in_sizes, int n_in,
                              void* d_out, int out_size, void* d_ws, size_t ws_size,
                              hipStream_t stream) {
  const float* H        = (const float*)d_in[0];
  const int*   edge     = (const int*)d_in[1];
  const int*   centers  = (const int*)d_in[2];
  const float* target   = (const float*)d_in[3];
  const float* ln_in_w  = (const float*)d_in[5];
  const float* ln1_w    = (const float*)d_in[6];
  const float* ln2_w    = (const float*)d_in[7];
  const float* w_qkv    = (const float*)d_in[8];
  const float* b_qkv    = (const float*)d_in[9];
  const float* w_o      = (const float*)d_in[10];
  const float* b_o      = (const float*)d_in[11];
  const float* w_gate   = (const float*)d_in[12];
  const float* w_up     = (const float*)d_in[13];
  const float* w_down   = (const float*)d_in[14];
  const float* w_head   = (const float*)d_in[15];
  const float* b_head   = (const float*)d_in[16];

  const int B = in_sizes[2];
  const int E = in_sizes[1] / 2;
  const int* dstE = edge + E;

  const size_t WB_ELEMS = 491520;
  const size_t NEED = WB_ELEMS*2 + (size_t)B*4;
  const bool useBf = (ws_size >= NEED);

  if (useBf) {
    unsigned short* wb = (unsigned short*)d_ws;
    float* partial = (float*)((char*)d_ws + WB_ELEMS*2);
    cvt_w<<<960, NTHREADS, 0, stream>>>(w_qkv, w_o, w_gate, w_up, w_down, w_head,
                                        ln_in_w, ln1_w, ln2_w, wb);
    smtp_center<true><<<B, NTHREADS, 0, stream>>>(H, dstE, centers, target, ln_in_w, ln1_w, ln2_w,
        w_qkv, b_qkv, w_o, b_o, w_gate, w_up, w_down, w_head, b_head, wb, partial);
    smtp_reduce<<<1, NTHREADS, 0, stream>>>(partial, B, (float*)d_out);
  } else {
    float* partial = (float*)d_ws;
    smtp_center<false><<<B, NTHREADS, 0, stream>>>(H, dstE, centers, target, ln_in_w, ln1_w, ln2_w,
        w_qkv, b_qkv, w_o, b_o, w_gate, w_up, w_down, w_head, b_head, (const unsigned short*)d_ws, partial);
    smtp_reduce<<<1, NTHREADS, 0, stream>>>(partial, B, (float*)d_out);
  }
}

// Round 15
// 1129.415 us; speedup vs baseline: 2.0962x; 2.0962x over previous
//
#include <hip/hip_runtime.h>

#define DM 256
#define NH 4
#define HD 64
#define DEG 32
#define LQ 33
#define DOUT 128
#define NTHREADS 256

typedef __attribute__((ext_vector_type(8))) short bf8v;   // 8 bf16 = 4 VGPRs (MFMA A/B frag)
typedef __attribute__((ext_vector_type(4))) float f4v;    // MFMA C/D frag

__device__ __forceinline__ float b2f(unsigned short u){ union{unsigned int i;float f;}v; v.i=((unsigned int)u)<<16; return v.f; }
__device__ __forceinline__ unsigned short f2b(float f){
  union{float f;unsigned int i;}v; v.f=f;
  unsigned int r=v.i+0x7FFFu+((v.i>>16)&1u);
  return (unsigned short)(r>>16);
}
__device__ __forceinline__ float wred(float x){
  #pragma unroll
  for (int o=32;o>=1;o>>=1) x += __shfl_xor(x,o,64);
  return x;
}

// XOR swizzles for bf16 LDS tiles (ds_read_b128 fragments; b64 writes stay in-chunk)
__device__ __forceinline__ int swz (int r, int c){ return r*DM + (((c>>3) ^ (r&7))<<3) + (c&7); } // [R][256]
__device__ __forceinline__ int swzV(int r, int c){ return r*HD + (((c>>3) ^ (r&7))<<3) + (c&7); } // [R][64]

// pack 4 f32 -> 4 bf16, one ds_write_b64 (dst 8B-aligned: col base %8 in {0,4})
__device__ __forceinline__ void packw(unsigned short* dst, float a0, float a1, float a2, float a3){
  unsigned int lo, hi;
  asm("v_cvt_pk_bf16_f32 %0,%1,%2" : "=v"(lo) : "v"(a0), "v"(a1));
  asm("v_cvt_pk_bf16_f32 %0,%1,%2" : "=v"(hi) : "v"(a2), "v"(a3));
  uint2 u; u.x = lo; u.y = hi;
  *(uint2*)dst = u;
}

// W[row][e..e+7] as bf16; fold1/fold2 only on the f32 fallback path
template<bool BF>
__device__ __forceinline__ bf8v wfrag(const float* Wf, const unsigned short* Wb,
                                      const float* fold1, const float* fold2, int row, int e){
  if constexpr (BF) {
    return *(const bf8v*)(Wb + (size_t)row*DM + e);
  } else {
    const float* p = Wf + (size_t)row*DM + e;
    float4 a = *(const float4*)p;
    float4 b = *(const float4*)(p+4);
    if (fold1) {
      const float4 fa = *(const float4*)(fold1+e), fb = *(const float4*)(fold1+e+4);
      a.x*=fa.x; a.y*=fa.y; a.z*=fa.z; a.w*=fa.w;
      b.x*=fb.x; b.y*=fb.y; b.z*=fb.z; b.w*=fb.w;
    }
    if (fold2) {
      const float4 fa = *(const float4*)(fold2+e), fb = *(const float4*)(fold2+e+4);
      a.x*=fa.x; a.y*=fa.y; a.z*=fa.z; a.w*=fa.w;
      b.x*=fb.x; b.y*=fb.y; b.z*=fb.z; b.w*=fb.w;
    }
    bf8v r;
    r[0]=(short)f2b(a.x); r[1]=(short)f2b(a.y); r[2]=(short)f2b(a.z); r[3]=(short)f2b(a.w);
    r[4]=(short)f2b(b.x); r[5]=(short)f2b(b.y); r[6]=(short)f2b(b.z); r[7]=(short)f2b(b.w);
    return r;
  }
}

__device__ __forceinline__ f4v mfma16(bf8v a, bf8v b, f4v c){
  return __builtin_amdgcn_mfma_f32_16x16x32_bf16(a, b, c, 0, 0, 0);
}

// R9 region map: A: Q[48][64] | K[48][64] | VT[64][64] -> mid[48][256] overlays [0,12288)
//                B: RB: AOall -> X1 -> Z [48][256]
#define U_Q  0
#define U_K  3072
#define U_VT 6144
#define RB   12288
#define U_SZ 24576

template<bool WBF16>
__global__ __launch_bounds__(NTHREADS, 2) void smtp_center(
    const float* __restrict__ H,
    const int* __restrict__ dstE,
    const int* __restrict__ centers,
    const float* __restrict__ target,
    const float* __restrict__ ln_in_w,
    const float* __restrict__ ln1_w,
    const float* __restrict__ ln2_w,
    const float* __restrict__ w_qkv,
    const float* __restrict__ b_qkv,
    const float* __restrict__ w_o,
    const float* __restrict__ b_o,
    const float* __restrict__ w_gate,
    const float* __restrict__ w_up,
    const float* __restrict__ w_down,
    const float* __restrict__ w_head,
    const float* __restrict__ b_head,
    const unsigned short* __restrict__ wb,
    float* __restrict__ partial)
{
  __shared__ __align__(16) unsigned short U[U_SZ];
  __shared__ __align__(16) unsigned short Hb[48*DM];  // raw H (bf16), swizzled [token][k]
  __shared__ float sS0[48];        // rsH (0 on pads)
  __shared__ float sS1[48];        // rsH*rs2 (QKV C-scale; 0 on pads)
  __shared__ float sRowSum[48*4];
  __shared__ int sIdx[48];
  __shared__ float sRed[4];

  const unsigned short* wbQKV = wb;
  const unsigned short* wbO   = wb + 196608;
  const unsigned short* wbG   = wb + 262144;
  const unsigned short* wbU   = wb + 327680;
  const unsigned short* wbD   = wb + 393216;
  const unsigned short* wbH   = wb + 458752;

  const int tid  = threadIdx.x;
  const int lane = tid & 63;
  const int wave = tid >> 6;
  const int bid  = blockIdx.x;
  const int l15  = lane & 15;
  const int l16  = (lane >> 4) * 8;
  const int rsub = (lane >> 4) * 4;

  // P0: star indices (pad rows -> 0, masked later by sS0/sS1 = 0)
  if (tid < 48) {
    int ctr = centers[bid];
    sIdx[tid] = (tid == 0) ? ctr : (tid < 1+DEG ? dstE[(size_t)ctr*DEG + (tid-1)] : 0);
  }
  __syncthreads();

  // P1 (R9-verified): stage H -> Hb (bf16) + per-row scales; VT pad keys 48..63 = 0
  for (int r = wave; r < 48; r += 4) {
    if (r < LQ) {
      const float4 x4 = ((const float4*)(H + (size_t)sIdx[r]*DM))[lane];
      const float4 wi = ((const float4*)ln_in_w)[lane];
      ushort4 hb; hb.x=f2b(x4.x); hb.y=f2b(x4.y); hb.z=f2b(x4.z); hb.w=f2b(x4.w);
      *(ushort4*)(Hb + swz(r, lane*4)) = hb;
      float ssh = x4.x*x4.x + x4.y*x4.y + x4.z*x4.z + x4.w*x4.w;
      const float w0 = x4.x*wi.x, w1 = x4.y*wi.y, w2 = x4.z*wi.z, w3 = x4.w*wi.w;
      float ssw = w0*w0 + w1*w1 + w2*w2 + w3*w3;
      ssh = wred(ssh);
      ssw = wred(ssw);
      if (lane == 0) {
        const float rsH = rsqrtf(ssh*(1.f/DM) + 1e-6f);
        const float rs2 = rsqrtf(rsH*rsH*ssw*(1.f/DM) + 1e-6f);
        sS0[r] = rsH;
        sS1[r] = rsH*rs2;
      }
    } else {
      ushort4 z4; z4.x=0; z4.y=0; z4.z=0; z4.w=0;
      *(ushort4*)(Hb + swz(r, lane*4)) = z4;
      if (lane == 0) { sS0[r] = 0.f; sS1[r] = 0.f; }
    }
  }
  if (tid < 128) {   // VT[64][64] keys 48..63 (chunks 6,7) = 0
    const int d = tid >> 1, ch = 6 + (tid & 1);
    *(uint4*)&U[U_VT + d*HD + ((ch ^ (d&7))<<3)] = make_uint4(0,0,0,0);
  }
  __syncthreads();

  // hoist QKV C-scale per fragment row
  float s1v[3][4];
  #pragma unroll
  for (int m = 0; m < 3; ++m)
    #pragma unroll
    for (int j = 0; j < 4; ++j)
      s1v[m][j] = sS1[m*16 + rsub + j];

  // P2 (R9-verified, normal orientation): per head QKV | bar | scores+softmax | bar | PV->AOall | bar
  for (int h = 0; h < NH; ++h) {
    // 2a QKV: M=48 x N=192, K=256; k-outer; C = s1[row]*(Hb @ Wqkv''^T) + b_qkv
    {
      int wrow[3], sect[3];
      #pragma unroll
      for (int t3 = 0; t3 < 3; ++t3) {
        const int t = wave*3 + t3;
        sect[t3] = t >> 2;                 // 0=Q 1=K 2=V
        wrow[t3] = sect[t3]*DM + h*HD + ((t*16 + l15) & 63);
      }
      f4v acc[3][3];
      #pragma unroll
      for (int t3 = 0; t3 < 3; ++t3)
        #pragma unroll
        for (int m = 0; m < 3; ++m)
          acc[t3][m] = (f4v){0.f,0.f,0.f,0.f};
      #pragma unroll
      for (int k = 0; k < 8; ++k) {
        bf8v aF[3];
        #pragma unroll
        for (int m = 0; m < 3; ++m)
          aF[m] = *(const bf8v*)(Hb + swz(m*16 + l15, k*32 + l16));
        #pragma unroll
        for (int t3 = 0; t3 < 3; ++t3) {
          const bf8v b = wfrag<WBF16>(w_qkv, wbQKV, ln_in_w, ln1_w, wrow[t3], k*32 + l16);
          #pragma unroll
          for (int m = 0; m < 3; ++m)
            acc[t3][m] = mfma16(aF[m], b, acc[t3][m]);
        }
      }
      #pragma unroll
      for (int t3 = 0; t3 < 3; ++t3) {
        const float bias = b_qkv[wrow[t3]];
        const int c = wrow[t3] & 63;
        if (sect[t3] == 2) {               // V -> VT[d][key]
          #pragma unroll
          for (int m = 0; m < 3; ++m)
            #pragma unroll
            for (int j = 0; j < 4; ++j)
              U[U_VT + swzV(c, m*16 + rsub + j)] = f2b(acc[t3][m][j]*s1v[m][j] + bias);
        } else {
          unsigned short* dstb = U + (sect[t3] ? U_K : U_Q);
          #pragma unroll
          for (int m = 0; m < 3; ++m)
            #pragma unroll
            for (int j = 0; j < 4; ++j)
              dstb[swzV(m*16 + rsub + j, c)] = f2b(acc[t3][m][j]*s1v[m][j] + bias);
        }
      }
    }
    __syncthreads();

    // 2b scores (waves 0-2) + in-register softmax + P write (own Q rows, overlays Q)
    if (wave < 3) {
      f4v s3[3];
      s3[0] = (f4v){0.f,0.f,0.f,0.f}; s3[1] = s3[0]; s3[2] = s3[0];
      #pragma unroll
      for (int kk = 0; kk < 2; ++kk) {
        const bf8v a = *(const bf8v*)(U + U_Q + swzV(wave*16 + l15, kk*32 + l16));
        #pragma unroll
        for (int nk = 0; nk < 3; ++nk) {
          const bf8v bb = *(const bf8v*)(U + U_K + swzV(nk*16 + l15, kk*32 + l16));
          s3[nk] = mfma16(a, bb, s3[nk]);
        }
      }
      #pragma unroll
      for (int j = 0; j < 4; ++j) {
        const float v0 = s3[0][j]*0.125f;
        const float v1 = s3[1][j]*0.125f;
        const float v2 = (l15 >= 1) ? -INFINITY : s3[2][j]*0.125f;  // keys 33..47 masked
        float mx = fmaxf(fmaxf(v0, v1), v2);
        mx = fmaxf(mx, __shfl_xor(mx, 1, 64));
        mx = fmaxf(mx, __shfl_xor(mx, 2, 64));
        mx = fmaxf(mx, __shfl_xor(mx, 4, 64));
        mx = fmaxf(mx, __shfl_xor(mx, 8, 64));
        const float e0 = __expf(v0 - mx), e1 = __expf(v1 - mx), e2 = __expf(v2 - mx);
        float den = e0 + e1 + e2;
        den += __shfl_xor(den, 1, 64);
        den += __shfl_xor(den, 2, 64);
        den += __shfl_xor(den, 4, 64);
        den += __shfl_xor(den, 8, 64);
        const float rn = 1.f / den;
        const int row = wave*16 + rsub + j;
        U[U_Q + swzV(row, 0*16 + l15)] = f2b(e0 * rn);
        U[U_Q + swzV(row, 1*16 + l15)] = f2b(e1 * rn);
        U[U_Q + swzV(row, 2*16 + l15)] = f2b(e2 * rn);
      }
    }
    __syncthreads();

    // 2c PV: O = P @ V -> AOall[:, h*64 + d]; wave = d-tile; K=64 (P48-63 x VT0 = 0)
    {
      f4v o4[3];
      o4[0] = (f4v){0.f,0.f,0.f,0.f}; o4[1] = o4[0]; o4[2] = o4[0];
      #pragma unroll
      for (int kk = 0; kk < 2; ++kk) {
        const bf8v bb = *(const bf8v*)(U + U_VT + swzV(wave*16 + l15, kk*32 + l16));
        #pragma unroll
        for (int mq = 0; mq < 3; ++mq) {
          const bf8v a = *(const bf8v*)(U + U_Q + swzV(mq*16 + l15, kk*32 + l16));
          o4[mq] = mfma16(a, bb, o4[mq]);
        }
      }
      #pragma unroll
      for (int mq = 0; mq < 3; ++mq)
        #pragma unroll
        for (int j = 0; j < 4; ++j)
          U[RB + swz(mq*16 + rsub + j, h*HD + wave*16 + l15)] = f2b(o4[mq][j]);
    }
    __syncthreads();
  }

  // ===== MLP half: SWAPPED orientation (w as A) + packed b64 C-writes (bisect target) =====

  // P3 WO swapped: X1^T = X0^T + Wo·AO^T; C-init from Hb; rowsums; X1 packed to RB
  {
    f4v acc[4][3];
    #pragma unroll
    for (int t4 = 0; t4 < 4; ++t4) {
      const int db = (wave*4 + t4)*16 + rsub;
      const float4 wi4 = *(const float4*)(ln_in_w + db);
      const float4 bo4 = *(const float4*)(b_o + db);
      #pragma unroll
      for (int m = 0; m < 3; ++m) {
        const int tok = m*16 + l15;
        const ushort4 x0 = *(const ushort4*)&Hb[swz(tok, db)];
        const float s0 = sS0[tok];
        acc[t4][m] = (f4v){ b2f(x0.x)*s0*wi4.x + bo4.x, b2f(x0.y)*s0*wi4.y + bo4.y,
                            b2f(x0.z)*s0*wi4.z + bo4.z, b2f(x0.w)*s0*wi4.w + bo4.w };
      }
    }
    #pragma unroll
    for (int k = 0; k < 8; ++k) {
      bf8v bA[3];
      #pragma unroll
      for (int m = 0; m < 3; ++m)
        bA[m] = *(const bf8v*)(U + RB + swz(m*16 + l15, k*32 + l16));
      #pragma unroll
      for (int t4 = 0; t4 < 4; ++t4) {
        const bf8v w = wfrag<WBF16>(w_o, wbO, nullptr, nullptr, (wave*4 + t4)*16 + l15, k*32 + l16);
        #pragma unroll
        for (int m = 0; m < 3; ++m)
          acc[t4][m] = mfma16(w, bA[m], acc[t4][m]);
      }
    }
    float p[3];
    #pragma unroll
    for (int m = 0; m < 3; ++m) {
      p[m] = 0.f;
      #pragma unroll
      for (int t4 = 0; t4 < 4; ++t4)
        #pragma unroll
        for (int j = 0; j < 4; ++j) p[m] += acc[t4][m][j]*acc[t4][m][j];
      p[m] += __shfl_xor(p[m], 16, 64);
      p[m] += __shfl_xor(p[m], 32, 64);
    }
    if (lane < 16) {
      #pragma unroll
      for (int m = 0; m < 3; ++m) sRowSum[(m*16 + l15)*4 + wave] = p[m];
    }
    __syncthreads();   // all AO reads done; rowsums visible
    #pragma unroll
    for (int t4 = 0; t4 < 4; ++t4)
      #pragma unroll
      for (int m = 0; m < 3; ++m)
        packw(&U[RB + swz(m*16 + l15, (wave*4 + t4)*16 + rsub)],
              acc[t4][m][0], acc[t4][m][1], acc[t4][m][2], acc[t4][m][3]);
  }
  __syncthreads();

  // P4 gate/up swapped: mid^T = silu(Wg·(rs3 X1)^T)*(Wu·(rs3 X1)^T) -> mid[token][md] packed
  #pragma unroll
  for (int p = 0; p < 2; ++p) {
    f4v aG[2][3], aU[2][3];
    #pragma unroll
    for (int tt = 0; tt < 2; ++tt)
      #pragma unroll
      for (int m = 0; m < 3; ++m) { aG[tt][m] = (f4v){0.f,0.f,0.f,0.f}; aU[tt][m] = aG[tt][m]; }
    #pragma unroll
    for (int k = 0; k < 8; ++k) {
      bf8v bX[3];
      #pragma unroll
      for (int m = 0; m < 3; ++m)
        bX[m] = *(const bf8v*)(U + RB + swz(m*16 + l15, k*32 + l16));
      #pragma unroll
      for (int tt = 0; tt < 2; ++tt) {
        const int wr = (wave*4 + p*2 + tt)*16 + l15;
        const bf8v bg = wfrag<WBF16>(w_gate, wbG, ln2_w, nullptr, wr, k*32 + l16);
        const bf8v bu = wfrag<WBF16>(w_up,   wbU, ln2_w, nullptr, wr, k*32 + l16);
        #pragma unroll
        for (int m = 0; m < 3; ++m) {
          aG[tt][m] = mfma16(bg, bX[m], aG[tt][m]);
          aU[tt][m] = mfma16(bu, bX[m], aU[tt][m]);
        }
      }
    }
    float rs3c[3];
    #pragma unroll
    for (int m = 0; m < 3; ++m) {
      const int tok = m*16 + l15;
      const float tot = sRowSum[tok*4+0] + sRowSum[tok*4+1] + sRowSum[tok*4+2] + sRowSum[tok*4+3];
      rs3c[m] = rsqrtf(tot*(1.f/DM) + 1e-6f);
    }
    #pragma unroll
    for (int tt = 0; tt < 2; ++tt)
      #pragma unroll
      for (int m = 0; m < 3; ++m) {
        float vv[4];
        #pragma unroll
        for (int j = 0; j < 4; ++j) {
          const float g = aG[tt][m][j]*rs3c[m];
          const float u = aU[tt][m][j]*rs3c[m];
          vv[j] = (g / (1.f + __expf(-g))) * u;
        }
        packw(&U[swz(m*16 + l15, (wave*4 + p*2 + tt)*16 + rsub)], vv[0], vv[1], vv[2], vv[3]);
      }
  }
  __syncthreads();

  // P5 down swapped: Z^T = X1^T + Wd·mid^T; in-place RB (wave-private cols)
  {
    f4v acc[4][3];
    #pragma unroll
    for (int t4 = 0; t4 < 4; ++t4) {
      const int db = (wave*4 + t4)*16 + rsub;
      #pragma unroll
      for (int m = 0; m < 3; ++m) {
        const ushort4 x1 = *(const ushort4*)&U[RB + swz(m*16 + l15, db)];
        acc[t4][m] = (f4v){ b2f(x1.x), b2f(x1.y), b2f(x1.z), b2f(x1.w) };
      }
    }
    #pragma unroll
    for (int k = 0; k < 8; ++k) {
      bf8v bM[3];
      #pragma unroll
      for (int m = 0; m < 3; ++m)
        bM[m] = *(const bf8v*)(U + swz(m*16 + l15, k*32 + l16));
      #pragma unroll
      for (int t4 = 0; t4 < 4; ++t4) {
        const bf8v w = wfrag<WBF16>(w_down, wbD, nullptr, nullptr, (wave*4 + t4)*16 + l15, k*32 + l16);
        #pragma unroll
        for (int m = 0; m < 3; ++m)
          acc[t4][m] = mfma16(w, bM[m], acc[t4][m]);
      }
    }
    #pragma unroll
    for (int t4 = 0; t4 < 4; ++t4)
      #pragma unroll
      for (int m = 0; m < 3; ++m)
        packw(&U[RB + swz(m*16 + l15, (wave*4 + t4)*16 + rsub)],
              acc[t4][m][0], acc[t4][m][1], acc[t4][m][2], acc[t4][m][3]);
  }
  __syncthreads();

  // P6 head swapped on tokens 1..32 + MSE (float4 target loads)
  float lsum = 0.f;
  {
    f4v acc[2][2];
    #pragma unroll
    for (int t2 = 0; t2 < 2; ++t2) {
      const float4 bh4 = *(const float4*)(b_head + (wave*2 + t2)*16 + rsub);
      #pragma unroll
      for (int m = 0; m < 2; ++m)
        acc[t2][m] = (f4v){ bh4.x, bh4.y, bh4.z, bh4.w };
    }
    #pragma unroll
    for (int k = 0; k < 8; ++k) {
      bf8v bZ[2];
      #pragma unroll
      for (int m = 0; m < 2; ++m)
        bZ[m] = *(const bf8v*)(U + RB + swz(1 + m*16 + l15, k*32 + l16));
      #pragma unroll
      for (int t2 = 0; t2 < 2; ++t2) {
        const bf8v w = wfrag<WBF16>(w_head, wbH, nullptr, nullptr, (wave*2 + t2)*16 + l15, k*32 + l16);
        #pragma unroll
        for (int m = 0; m < 2; ++m)
          acc[t2][m] = mfma16(w, bZ[m], acc[t2][m]);
      }
    }
    #pragma unroll
    for (int t2 = 0; t2 < 2; ++t2)
      #pragma unroll
      for (int m = 0; m < 2; ++m) {
        const int tok = 1 + m*16 + l15;      // 1..32
        const float4 tv = *(const float4*)&target[(size_t)sIdx[tok]*DOUT + (wave*2 + t2)*16 + rsub];
        const float d0 = acc[t2][m][0] - tv.x;
        const float d1 = acc[t2][m][1] - tv.y;
        const float d2 = acc[t2][m][2] - tv.z;
        const float d3 = acc[t2][m][3] - tv.w;
        lsum += d0*d0 + d1*d1 + d2*d2 + d3*d3;
      }
  }
  lsum = wred(lsum);
  if (lane == 0) sRed[wave] = lsum;
  __syncthreads();
  if (tid == 0)
    partial[bid] = (sRed[0]+sRed[1]+sRed[2]+sRed[3]) * (1.f/(DEG*DOUT));
}

// one-time f32 -> bf16 weight conversion with RMSNorm folding (k-dim)
__global__ void cvt_w(const float* __restrict__ qkv, const float* __restrict__ o,
                      const float* __restrict__ g, const float* __restrict__ u,
                      const float* __restrict__ dn, const float* __restrict__ hd,
                      const float* __restrict__ lin, const float* __restrict__ l1,
                      const float* __restrict__ l2,
                      unsigned short* __restrict__ out)
{
  const int i = blockIdx.x*NTHREADS + threadIdx.x;
  const int e = i*2;
  if (e >= 491520) return;
  const float* src; int off;
  float f0 = 1.f, f1 = 1.f;
  if      (e < 196608){ src=qkv; off=e;        const int c=off&255; f0=lin[c]*l1[c]; f1=lin[c+1]*l1[c+1]; }
  else if (e < 262144){ src=o;  off=e-196608; }
  else if (e < 327680){ src=g;  off=e-262144;  const int c=off&255; f0=l2[c]; f1=l2[c+1]; }
  else if (e < 393216){ src=u;  off=e-327680;  const int c=off&255; f0=l2[c]; f1=l2[c+1]; }
  else if (e < 458752){ src=dn; off=e-393216; }
  else                { src=hd; off=e-458752; }
  const float2 v = *(const float2*)(src + off);
  const unsigned int pk = (unsigned int)f2b(v.x*f0) | ((unsigned int)f2b(v.y*f1) << 16);
  *(unsigned int*)(out + e) = pk;
}

__global__ void smtp_reduce(const float* __restrict__ partial, int B, float* __restrict__ out)
{
  __shared__ float sRed[4];
  const int tid = threadIdx.x;
  float s = 0.f;
  for (int i = tid; i < B; i += NTHREADS) s += partial[i];
  s = wred(s);
  if ((tid & 63) == 0) sRed[tid>>6] = s;
  __syncthreads();
  if (tid == 0) out[0] = (sRed[0]+sRed[1]+sRed[2]+sRed[3]) / (float)B;
}

extern "C" void kernel_launch(void* const* d_in, const int* in_sizes, int n_in,
                              void* d_out, int out_size, void* d_ws, size_t ws_size,
                              hipStream_t stream) {
  const float* H        = (const float*)d_in[0];
  const int*   edge     = (const int*)d_in[1];
  const int*   centers  = (const int*)d_in[2];
  const float* target   = (const float*)d_in[3];
  const float* ln_in_w  = (const float*)d_in[5];
  const float* ln1_w    = (const float*)d_in[6];
  const float* ln2_w    = (const float*)d_in[7];
  const float* w_qkv    = (const float*)d_in[8];
  const float* b_qkv    = (const float*)d_in[9];
  const float* w_o      = (const float*)d_in[10];
  const float* b_o      = (const float*)d_in[11];
  const float* w_gate   = (const float*)d_in[12];
  const float* w_up     = (const float*)d_in[13];
  const float* w_down   = (const float*)d_in[14];
  const float* w_head   = (const float*)d_in[15];
  const float* b_head   = (const float*)d_in[16];

  const int B = in_sizes[2];
  const int E = in_sizes[1] / 2;
  const int* dstE = edge + E;

  const size_t WB_ELEMS = 491520;
  const size_t NEED = WB_ELEMS*2 + (size_t)B*4;
  const bool useBf = (ws_size >= NEED);

  if (useBf) {
    unsigned short* wb = (unsigned short*)d_ws;
    float* partial = (float*)((char*)d_ws + WB_ELEMS*2);
    cvt_w<<<960, NTHREADS, 0, stream>>>(w_qkv, w_o, w_gate, w_up, w_down, w_head,
                                        ln_in_w, ln1_w, ln2_w, wb);
    smtp_center<true><<<B, NTHREADS, 0, stream>>>(H, dstE, centers, target, ln_in_w, ln1_w, ln2_w,
        w_qkv, b_qkv, w_o, b_o, w_gate, w_up, w_down, w_head, b_head, wb, partial);
    smtp_reduce<<<1, NTHREADS, 0, stream>>>(partial, B, (float*)d_out);
  } else {
    float* partial = (float*)d_ws;
    smtp_center<false><<<B, NTHREADS, 0, stream>>>(H, dstE, centers, target, ln_in_w, ln1_w, ln2_w,
        w_qkv, b_qkv, w_o, b_o, w_gate, w_up, w_down, w_head, b_head, (const unsigned short*)d_ws, partial);
    smtp_reduce<<<1, NTHREADS, 0, stream>>>(partial, B, (float*)d_out);
  }
}